// Round 5
// baseline (123.510 us; speedup 1.0000x reference)
//
#include <hip/hip_runtime.h>

#define TPB 256

constexpr int NSEQ = 32768;
constexpr int C0   = 4096;               // output samples per block chunk (8 chunks/batch)
constexpr float SCG = 14.4269504089f;    // 10 * log2(e)

// Analysis halos h_l = 2*h_{l+1}+3, h5=4 -> {221,109,53,25,11,4} (h0 applies to x window)
// C0=4096 per-channel valid lengths: {2266,1130,562,278,136}; padded P: {2272,1136,568,280,136}
// Parity arrays per channel [E|O], LE = P_next+4: LE={2276,1140,572,284,140}
// Level-5 out contiguous stride 136; synthesis strides {264,520,1032,2056}
// bufA: L0(4552) L2(4576) L4(4480) recon4(4224) recon2(4128)  -> 4576
// bufB: L1(4560) L3(4544) L5(4352) recon3(4160) recon1(4112)  -> 4560

__device__ __forceinline__ float4 ldf4(const float* p) { return *reinterpret_cast<const float4*>(p); }
__device__ __forceinline__ void   stf4(float* p, const float4 v) { *reinterpret_cast<float4*>(p) = v; }

// v * (sigmoid(10(y-b)) + sigmoid(-10(y+b))), tb = SCG*b precomputed
__device__ __forceinline__ float gated(float y, float tb) {
    float e1 = __builtin_amdgcn_exp2f(fmaf(y, -SCG, tb));
    float e2 = __builtin_amdgcn_exp2f(fmaf(y,  SCG, tb));
    return y * (__builtin_amdgcn_rcpf(1.f + e1) + __builtin_amdgcn_rcpf(1.f + e2));
}

// Analysis level, r=8: task = 8 outputs for sibling channels 2c,2c+1.
// y_i = sum_u A[i+u]*K[2u] + B[i+BOFF+u]*K[2u+1]
//   levels 2..5 (BOFF=0): A=E, B=O (local-index parity)
//   level 1    (BOFF=1): A=O, B=E (window base s-222)
// LAST=false: parity out (E|O, stride 2*LEout); LAST=true: contiguous out stride LEout.
template<int LEin, int LEout, int P, int PAIRS, int Nlev, int BOFF, bool EDGE, bool LAST>
__device__ __forceinline__ void analysis8(
    const float* __restrict__ in, float* __restrict__ out,
    const float* __restrict__ kf, const float* __restrict__ bias, int outBase)
{
    constexpr int TPC = P / 8;
    constexpr int TOT = PAIRS * TPC;
    for (int task = threadIdx.x; task < TOT; task += TPB) {
        const int c  = task / TPC;
        const int i0 = (task - c * TPC) * 8;

        const float* pe = in + c * (2 * LEin);
        const float* pa = BOFF ? (pe + LEin) : pe;
        const float* pb = BOFF ? pe : (pe + LEin);

        float a[12], b[12];
        reinterpret_cast<float4*>(a)[0] = ldf4(pa + i0);
        reinterpret_cast<float4*>(a)[1] = ldf4(pa + i0 + 4);
        reinterpret_cast<float4*>(a)[2] = ldf4(pa + i0 + 8);
        reinterpret_cast<float4*>(b)[0] = ldf4(pb + i0);
        reinterpret_cast<float4*>(b)[1] = ldf4(pb + i0 + 4);
        reinterpret_cast<float4*>(b)[2] = ldf4(pb + i0 + 8);

        float k0[8], k1[8];
        {
            const float* kp = kf + (2 * c) * 8;
            reinterpret_cast<float4*>(k0)[0] = ldf4(kp);
            reinterpret_cast<float4*>(k0)[1] = ldf4(kp + 4);
            reinterpret_cast<float4*>(k1)[0] = ldf4(kp + 8);
            reinterpret_cast<float4*>(k1)[1] = ldf4(kp + 12);
        }
        const float tb0 = bias[2 * c];
        const float tb1 = bias[2 * c + 1];

        float v0[8], v1[8];
#pragma unroll
        for (int r = 0; r < 8; ++r) {
            float ya = 0.f, yb = 0.f;
#pragma unroll
            for (int u = 0; u < 4; ++u) {
                ya = fmaf(a[r + u], k0[2 * u], ya);
                ya = fmaf(b[r + BOFF + u], k0[2 * u + 1], ya);
                yb = fmaf(a[r + u], k1[2 * u], yb);
                yb = fmaf(b[r + BOFF + u], k1[2 * u + 1], yb);
            }
            float w0 = gated(ya, tb0);
            float w1 = gated(yb, tb1);
            if (EDGE) {
                const bool ok = ((unsigned)(outBase + i0 + r) < (unsigned)Nlev);
                w0 = ok ? w0 : 0.f;
                w1 = ok ? w1 : 0.f;
            }
            v0[r] = w0; v1[r] = w1;
        }

        if (LAST) {
            float* o0 = out + (2 * c) * LEout + i0;
            float* o1 = out + (2 * c + 1) * LEout + i0;
            stf4(o0,     make_float4(v0[0], v0[1], v0[2], v0[3]));
            stf4(o0 + 4, make_float4(v0[4], v0[5], v0[6], v0[7]));
            stf4(o1,     make_float4(v1[0], v1[1], v1[2], v1[3]));
            stf4(o1 + 4, make_float4(v1[4], v1[5], v1[6], v1[7]));
        } else {
            const int j0 = i0 >> 1;
            float* ob0 = out + (2 * c) * (2 * LEout);
            float* ob1 = ob0 + 2 * LEout;
            stf4(ob0 + j0,         make_float4(v0[0], v0[2], v0[4], v0[6]));
            stf4(ob0 + LEout + j0, make_float4(v0[1], v0[3], v0[5], v0[7]));
            stf4(ob1 + j0,         make_float4(v1[0], v1[2], v1[4], v1[6]));
            stf4(ob1 + LEout + j0, make_float4(v1[1], v1[3], v1[5], v1[7]));
        }
    }
}

// Synthesis, r=8 (R4-validated formula): out[g,nl] = sum_q y0[j0+q]K0[kb-2q] + y1[j0+q]K1[kb-2q]
// j0 = (nl+1)>>1 (local, both buffers at global-4 base), kb = 7-(nl&1).
template<int Sin, int Sout, int P, int G, int Nlev, bool EDGE>
__device__ __forceinline__ void synth8(
    const float* __restrict__ in, float* __restrict__ out,
    const float* __restrict__ kf, int outBase)
{
    constexpr int TPG = P / 8;
    constexpr int TOT = G * TPG;
    for (int task = threadIdx.x; task < TOT; task += TPB) {
        const int g   = task / TPG;
        const int nl0 = (task - g * TPG) * 8;

        float ya[8], yb[8];
        {
            const float* p0 = in + (2 * g) * Sin + nl0 / 2;
            const float* p1 = p0 + Sin;
            reinterpret_cast<float4*>(ya)[0] = ldf4(p0);
            reinterpret_cast<float4*>(ya)[1] = ldf4(p0 + 4);
            reinterpret_cast<float4*>(yb)[0] = ldf4(p1);
            reinterpret_cast<float4*>(yb)[1] = ldf4(p1 + 4);
        }
        float k0[8], k1[8];
        {
            const float* kp = kf + (2 * g) * 8;
            reinterpret_cast<float4*>(k0)[0] = ldf4(kp);
            reinterpret_cast<float4*>(k0)[1] = ldf4(kp + 4);
            reinterpret_cast<float4*>(k1)[0] = ldf4(kp + 8);
            reinterpret_cast<float4*>(k1)[1] = ldf4(kp + 12);
        }

        float o[8];
#pragma unroll
        for (int r = 0; r < 8; ++r) {
            const int jr = (r + 1) >> 1;
            const int kb = 7 - (r & 1);
            float acc = 0.f;
#pragma unroll
            for (int q = 0; q < 4; ++q) {
                acc = fmaf(ya[jr + q], k0[kb - 2 * q], acc);
                acc = fmaf(yb[jr + q], k1[kb - 2 * q], acc);
            }
            if (EDGE) {
                const bool ok = ((unsigned)(outBase + nl0 + r) < (unsigned)Nlev);
                acc = ok ? acc : 0.f;
            }
            o[r] = acc;
        }
        float* op = out + g * Sout + nl0;
        stf4(op,     make_float4(o[0], o[1], o[2], o[3]));
        stf4(op + 4, make_float4(o[4], o[5], o[6], o[7]));
    }
}

template<bool EDGE>
__device__ __forceinline__ void run_chunk(
    const float* __restrict__ xb, float* __restrict__ ob, int s,
    float* __restrict__ bufA, float* __restrict__ bufB,
    const float* __restrict__ kf, const float* __restrict__ bss)
{
    const int tid = threadIdx.x;

    // Stage x window [s-222 ..] parity-split: E[j]=x[s-222+2j] (bufA[0..2275]), O (bufA[2276..])
    {
        const int b0 = s - 222;
        if (EDGE) {
            for (int t = tid; t < 1138; t += TPB) {
                const int g = b0 + 4 * t;
                const float e0 = ((unsigned)g       < (unsigned)NSEQ) ? xb[g]     : 0.f;
                const float o0 = ((unsigned)(g + 1) < (unsigned)NSEQ) ? xb[g + 1] : 0.f;
                const float e1 = ((unsigned)(g + 2) < (unsigned)NSEQ) ? xb[g + 2] : 0.f;
                const float o1 = ((unsigned)(g + 3) < (unsigned)NSEQ) ? xb[g + 3] : 0.f;
                *reinterpret_cast<float2*>(bufA + 2 * t)        = make_float2(e0, e1);
                *reinterpret_cast<float2*>(bufA + 2276 + 2 * t) = make_float2(o0, o1);
            }
        } else {
            for (int t = tid; t < 1138; t += TPB) {
                const float* p = xb + b0 + 4 * t;
                const float2 fa = *reinterpret_cast<const float2*>(p);
                const float2 fb = *reinterpret_cast<const float2*>(p + 2);
                *reinterpret_cast<float2*>(bufA + 2 * t)        = make_float2(fa.x, fb.x);
                *reinterpret_cast<float2*>(bufA + 2276 + 2 * t) = make_float2(fa.y, fb.y);
            }
        }
    }
    __syncthreads();

    // ---- analysis ----
    analysis8<2276, 1140, 2272,  1, 16384, 1, EDGE, false>(bufA, bufB, kf + 0,   bss + 0,  (s >> 1) - 109);
    __syncthreads();
    analysis8<1140,  572, 1136,  2,  8192, 0, EDGE, false>(bufB, bufA, kf + 16,  bss + 2,  (s >> 2) - 53);
    __syncthreads();
    analysis8< 572,  284,  568,  4,  4096, 0, EDGE, false>(bufA, bufB, kf + 48,  bss + 6,  (s >> 3) - 25);
    __syncthreads();
    analysis8< 284,  140,  280,  8,  2048, 0, EDGE, false>(bufB, bufA, kf + 112, bss + 14, (s >> 4) - 11);
    __syncthreads();
    analysis8< 140,  136,  136, 16,  1024, 0, EDGE, true >(bufA, bufB, kf + 240, bss + 30, (s >> 5) - 4);
    __syncthreads();

    // ---- synthesis ----
    synth8< 136,  264,  264, 16,  2048, EDGE>(bufB, bufA, kf + 240, (s >> 4) - 4);
    __syncthreads();
    synth8< 264,  520,  520,  8,  4096, EDGE>(bufA, bufB, kf + 112, (s >> 3) - 4);
    __syncthreads();
    synth8< 520, 1032, 1032,  4,  8192, EDGE>(bufB, bufA, kf + 48,  (s >> 2) - 4);
    __syncthreads();
    synth8<1032, 2056, 2056,  2, 16384, EDGE>(bufA, bufB, kf + 16,  (s >> 1) - 4);
    __syncthreads();

    // ---- final level (G=1) straight to global; recon1 in bufB, stride 2056, base s/2-4 ----
    for (int task = tid; task < 512; task += TPB) {
        const int i0 = task * 8;
        float ya[12], yb[12];
        {
            const float* p0 = bufB + i0 / 2;
            const float* p1 = p0 + 2056;
            reinterpret_cast<float4*>(ya)[0] = ldf4(p0);
            reinterpret_cast<float4*>(ya)[1] = ldf4(p0 + 4);
            reinterpret_cast<float4*>(ya)[2] = ldf4(p0 + 8);
            reinterpret_cast<float4*>(yb)[0] = ldf4(p1);
            reinterpret_cast<float4*>(yb)[1] = ldf4(p1 + 4);
            reinterpret_cast<float4*>(yb)[2] = ldf4(p1 + 8);
        }
        float k0[8], k1[8];
        reinterpret_cast<float4*>(k0)[0] = ldf4(kf);
        reinterpret_cast<float4*>(k0)[1] = ldf4(kf + 4);
        reinterpret_cast<float4*>(k1)[0] = ldf4(kf + 8);
        reinterpret_cast<float4*>(k1)[1] = ldf4(kf + 12);

        float o[8];
#pragma unroll
        for (int r = 0; r < 8; ++r) {
            const int jr = ((r + 1) >> 1) + 2;
            const int kb = 7 - (r & 1);
            float acc = 0.f;
#pragma unroll
            for (int q = 0; q < 4; ++q) {
                acc = fmaf(ya[jr + q], k0[kb - 2 * q], acc);
                acc = fmaf(yb[jr + q], k1[kb - 2 * q], acc);
            }
            o[r] = acc;
        }
        stf4(ob + i0,     make_float4(o[0], o[1], o[2], o[3]));
        stf4(ob + i0 + 4, make_float4(o[4], o[5], o[6], o[7]));
    }
}

__global__ __launch_bounds__(TPB) void wpt_fused(
    const float* __restrict__ x,
    const float* __restrict__ K1, const float* __restrict__ K2,
    const float* __restrict__ K3, const float* __restrict__ K4,
    const float* __restrict__ K5,
    const float* __restrict__ B1, const float* __restrict__ B2,
    const float* __restrict__ B3, const float* __restrict__ B4,
    const float* __restrict__ B5,
    float* __restrict__ out)
{
    __shared__ __align__(16) float bufA[4576];
    __shared__ __align__(16) float bufB[4560];
    __shared__ __align__(16) float kf[496];
    __shared__ float bss[62];

    const int tid   = threadIdx.x;
    const int batch = blockIdx.x >> 3;
    const int cid   = blockIdx.x & 7;
    const int s     = cid * C0;

    {
        const float* kin[5] = {K1, K2, K3, K4, K5};
        const float* bin[5] = {B1, B2, B3, B4, B5};
        const int koff[5] = {0, 16, 48, 112, 240};
        const int boff[5] = {0, 2, 6, 14, 30};
#pragma unroll
        for (int l = 0; l < 5; ++l) {
            for (int i = tid; i < (16 << l); i += TPB) kf[koff[l] + i] = kin[l][i];
            for (int i = tid; i < (2  << l); i += TPB) bss[boff[l] + i] = SCG * bin[l][i];
        }
    }

    const float* xb = x + batch * NSEQ;
    float* ob = out + batch * NSEQ + s;

    if (cid == 0 || cid == 7)
        run_chunk<true >(xb, ob, s, bufA, bufB, kf, bss);
    else
        run_chunk<false>(xb, ob, s, bufA, bufB, kf, bss);
}

extern "C" void kernel_launch(void* const* d_in, const int* in_sizes, int n_in,
                              void* d_out, int out_size, void* d_ws, size_t ws_size,
                              hipStream_t stream) {
    const int nbatch = in_sizes[0] / NSEQ;
    wpt_fused<<<dim3(nbatch * (NSEQ / C0)), dim3(TPB), 0, stream>>>(
        (const float*)d_in[0],
        (const float*)d_in[1], (const float*)d_in[2],
        (const float*)d_in[3], (const float*)d_in[4],
        (const float*)d_in[5],
        (const float*)d_in[6], (const float*)d_in[7],
        (const float*)d_in[8], (const float*)d_in[9],
        (const float*)d_in[10],
        (float*)d_out);
}

// Round 6
// 120.592 us; speedup vs baseline: 1.0242x; 1.0242x over previous
//
#include <hip/hip_runtime.h>

#define TPB 256

constexpr int NSEQ = 32768;
constexpr int C0   = 2048;               // output samples per block chunk (16 chunks/batch)
constexpr float SCG = 14.4269504089f;    // 10 * log2(e)

// Analysis halos h_l = 2*h_{l+1}+3, h5=4 -> {221,109,53,25,11,4}
// C0=2048 per-channel padded lengths P: {1248,624,312,152,72}
// Parity arrays per channel [E|O], LE = P_next+4: {1252,628,316,156,76}; L5 contiguous stride 72
// Synthesis strides {136,264,520,1032}
// bufA: L0(2504) L2(2528) L4(2432) recon4(2176) recon2(2080) -> 2528
// bufB: L1(2512) L3(2496) L5(2304) recon3(2112) recon1(2064) -> 2512
// LDS total: 2528+2512+62 floats = 20408 B -> 8 blocks/CU.
// All filter rows are k_lp or k_hp (row r is lp iff (r&1)==((r>>1)&1)); both held in SGPRs.

__device__ __forceinline__ float4 ldf4(const float* p) { return *reinterpret_cast<const float4*>(p); }
__device__ __forceinline__ void   stf4(float* p, const float4 v) { *reinterpret_cast<float4*>(p) = v; }

__device__ __forceinline__ float rfl(float x) {
    return __builtin_bit_cast(float, __builtin_amdgcn_readfirstlane(__builtin_bit_cast(int, x)));
}

// y * (sigmoid(10(y-b)) + sigmoid(-10(y+b))), tb = SCG*b precomputed
__device__ __forceinline__ float gated(float y, float tb) {
    float e1 = __builtin_amdgcn_exp2f(fmaf(y, -SCG, tb));
    float e2 = __builtin_amdgcn_exp2f(fmaf(y,  SCG, tb));
    return y * (__builtin_amdgcn_rcpf(1.f + e1) + __builtin_amdgcn_rcpf(1.f + e2));
}

// Analysis level, r=8: task = 8 outputs for sibling channels 2c,2c+1.
// Channel 2c+(c&1) uses lp, channel 2c+1-(c&1) uses hp (QMF row-parity rule).
// y_i = sum_u A[i+u]*k[2u] + B[i+BOFF+u]*k[2u+1]; L1 (BOFF=1): A=O, B=E (base s-222);
// deeper (BOFF=0): A=E, B=O.  LAST: contiguous out stride LEout, else parity out.
template<int LEin, int LEout, int P, int PAIRS, int Nlev, int BOFF, bool EDGE, bool LAST>
__device__ __forceinline__ void analysis8(
    const float* __restrict__ in, float* __restrict__ out,
    const float* __restrict__ lp, const float* __restrict__ hp,
    const float* __restrict__ bias, int outBase)
{
    constexpr int TPC = P / 8;
    constexpr int TOT = PAIRS * TPC;
    for (int task = threadIdx.x; task < TOT; task += TPB) {
        const int c  = task / TPC;
        const int i0 = (task - c * TPC) * 8;

        const float* pe = in + c * (2 * LEin);
        const float* pa = BOFF ? (pe + LEin) : pe;
        const float* pb = BOFF ? pe : (pe + LEin);

        float a[12], b[12];
        reinterpret_cast<float4*>(a)[0] = ldf4(pa + i0);
        reinterpret_cast<float4*>(a)[1] = ldf4(pa + i0 + 4);
        reinterpret_cast<float4*>(a)[2] = ldf4(pa + i0 + 8);
        reinterpret_cast<float4*>(b)[0] = ldf4(pb + i0);
        reinterpret_cast<float4*>(b)[1] = ldf4(pb + i0 + 4);
        reinterpret_cast<float4*>(b)[2] = ldf4(pb + i0 + 8);

        const int sw     = c & 1;
        const int ch_lp  = 2 * c + sw;
        const int ch_hp  = 2 * c + 1 - sw;
        const float tb_l = bias[ch_lp];
        const float tb_h = bias[ch_hp];

        float vl[8], vh[8];
#pragma unroll
        for (int r = 0; r < 8; ++r) {
            float yl = 0.f, yh = 0.f;
#pragma unroll
            for (int u = 0; u < 4; ++u) {
                yl = fmaf(a[r + u], lp[2 * u], yl);
                yl = fmaf(b[r + BOFF + u], lp[2 * u + 1], yl);
                yh = fmaf(a[r + u], hp[2 * u], yh);
                yh = fmaf(b[r + BOFF + u], hp[2 * u + 1], yh);
            }
            float wl = gated(yl, tb_l);
            float wh = gated(yh, tb_h);
            if (EDGE) {
                const bool ok = ((unsigned)(outBase + i0 + r) < (unsigned)Nlev);
                wl = ok ? wl : 0.f;
                wh = ok ? wh : 0.f;
            }
            vl[r] = wl; vh[r] = wh;
        }

        if (LAST) {
            float* ol = out + ch_lp * LEout + i0;
            float* oh = out + ch_hp * LEout + i0;
            stf4(ol,     make_float4(vl[0], vl[1], vl[2], vl[3]));
            stf4(ol + 4, make_float4(vl[4], vl[5], vl[6], vl[7]));
            stf4(oh,     make_float4(vh[0], vh[1], vh[2], vh[3]));
            stf4(oh + 4, make_float4(vh[4], vh[5], vh[6], vh[7]));
        } else {
            const int j0 = i0 >> 1;
            float* ol = out + ch_lp * (2 * LEout);
            float* oh = out + ch_hp * (2 * LEout);
            stf4(ol + j0,         make_float4(vl[0], vl[2], vl[4], vl[6]));
            stf4(ol + LEout + j0, make_float4(vl[1], vl[3], vl[5], vl[7]));
            stf4(oh + j0,         make_float4(vh[0], vh[2], vh[4], vh[6]));
            stf4(oh + LEout + j0, make_float4(vh[1], vh[3], vh[5], vh[7]));
        }
    }
}

// Synthesis, r=8: out[g,nl] = sum_q y_lp[j0+q]*lp[kb-2q] + y_hp[j0+q]*hp[kb-2q]
// lp-channel of group g is 2g+(g&1). j0=(nl+1)>>1 local, kb=7-(nl&1).
template<int Sin, int Sout, int P, int G, int Nlev, bool EDGE>
__device__ __forceinline__ void synth8(
    const float* __restrict__ in, float* __restrict__ out,
    const float* __restrict__ lp, const float* __restrict__ hp, int outBase)
{
    constexpr int TPG = P / 8;
    constexpr int TOT = G * TPG;
    for (int task = threadIdx.x; task < TOT; task += TPB) {
        const int g   = task / TPG;
        const int nl0 = (task - g * TPG) * 8;
        const int sw  = g & 1;

        float ya[8], yb[8];
        {
            const float* p0 = in + (2 * g + sw)     * Sin + nl0 / 2;   // lp channel
            const float* p1 = in + (2 * g + 1 - sw) * Sin + nl0 / 2;   // hp channel
            reinterpret_cast<float4*>(ya)[0] = ldf4(p0);
            reinterpret_cast<float4*>(ya)[1] = ldf4(p0 + 4);
            reinterpret_cast<float4*>(yb)[0] = ldf4(p1);
            reinterpret_cast<float4*>(yb)[1] = ldf4(p1 + 4);
        }

        float o[8];
#pragma unroll
        for (int r = 0; r < 8; ++r) {
            const int jr = (r + 1) >> 1;
            const int kb = 7 - (r & 1);
            float acc = 0.f;
#pragma unroll
            for (int q = 0; q < 4; ++q) {
                acc = fmaf(ya[jr + q], lp[kb - 2 * q], acc);
                acc = fmaf(yb[jr + q], hp[kb - 2 * q], acc);
            }
            if (EDGE) {
                const bool ok = ((unsigned)(outBase + nl0 + r) < (unsigned)Nlev);
                acc = ok ? acc : 0.f;
            }
            o[r] = acc;
        }
        float* op = out + g * Sout + nl0;
        stf4(op,     make_float4(o[0], o[1], o[2], o[3]));
        stf4(op + 4, make_float4(o[4], o[5], o[6], o[7]));
    }
}

template<bool EDGE>
__device__ __forceinline__ void run_chunk(
    const float* __restrict__ xb, float* __restrict__ ob, int s,
    float* __restrict__ bufA, float* __restrict__ bufB,
    const float* __restrict__ lp, const float* __restrict__ hp,
    const float* __restrict__ bss)
{
    const int tid = threadIdx.x;

    // Stage x window [s-222 ..] parity-split by GLOBAL parity:
    // E[j]=x[s-222+2j] (bufA[0..1251]), O[j]=x[s-222+2j+1] (bufA[1252..2503])
    {
        const int b0 = s - 222;
        if (EDGE) {
            for (int t = tid; t < 626; t += TPB) {
                const int g = b0 + 4 * t;
                const float e0 = ((unsigned)g       < (unsigned)NSEQ) ? xb[g]     : 0.f;
                const float o0 = ((unsigned)(g + 1) < (unsigned)NSEQ) ? xb[g + 1] : 0.f;
                const float e1 = ((unsigned)(g + 2) < (unsigned)NSEQ) ? xb[g + 2] : 0.f;
                const float o1 = ((unsigned)(g + 3) < (unsigned)NSEQ) ? xb[g + 3] : 0.f;
                *reinterpret_cast<float2*>(bufA + 2 * t)        = make_float2(e0, e1);
                *reinterpret_cast<float2*>(bufA + 1252 + 2 * t) = make_float2(o0, o1);
            }
        } else {
            for (int t = tid; t < 626; t += TPB) {
                const float* p = xb + b0 + 4 * t;
                const float2 fa = *reinterpret_cast<const float2*>(p);
                const float2 fb = *reinterpret_cast<const float2*>(p + 2);
                *reinterpret_cast<float2*>(bufA + 2 * t)        = make_float2(fa.x, fb.x);
                *reinterpret_cast<float2*>(bufA + 1252 + 2 * t) = make_float2(fa.y, fb.y);
            }
        }
    }
    __syncthreads();

    // ---- analysis ----
    analysis8<1252, 628, 1248,  1, 16384, 1, EDGE, false>(bufA, bufB, lp, hp, bss + 0,  (s >> 1) - 109);
    __syncthreads();
    analysis8< 628, 316,  624,  2,  8192, 0, EDGE, false>(bufB, bufA, lp, hp, bss + 2,  (s >> 2) - 53);
    __syncthreads();
    analysis8< 316, 156,  312,  4,  4096, 0, EDGE, false>(bufA, bufB, lp, hp, bss + 6,  (s >> 3) - 25);
    __syncthreads();
    analysis8< 156,  76,  152,  8,  2048, 0, EDGE, false>(bufB, bufA, lp, hp, bss + 14, (s >> 4) - 11);
    __syncthreads();
    analysis8<  76,  72,   72, 16,  1024, 0, EDGE, true >(bufA, bufB, lp, hp, bss + 30, (s >> 5) - 4);
    __syncthreads();

    // ---- synthesis ----
    synth8<  72,  136,  136, 16,  2048, EDGE>(bufB, bufA, lp, hp, (s >> 4) - 4);
    __syncthreads();
    synth8< 136,  264,  264,  8,  4096, EDGE>(bufA, bufB, lp, hp, (s >> 3) - 4);
    __syncthreads();
    synth8< 264,  520,  520,  4,  8192, EDGE>(bufB, bufA, lp, hp, (s >> 2) - 4);
    __syncthreads();
    synth8< 520, 1032, 1032,  2, 16384, EDGE>(bufA, bufB, lp, hp, (s >> 1) - 4);
    __syncthreads();

    // ---- final level (G=1) straight to global; recon1 in bufB, stride 1032, base s/2-4 ----
    {
        const int i0 = tid * 8;              // 256 tasks exactly
        float ya[12], yb[12];
        {
            const float* p0 = bufB + i0 / 2;          // channel 0 = lp
            const float* p1 = p0 + 1032;              // channel 1 = hp
            reinterpret_cast<float4*>(ya)[0] = ldf4(p0);
            reinterpret_cast<float4*>(ya)[1] = ldf4(p0 + 4);
            reinterpret_cast<float4*>(ya)[2] = ldf4(p0 + 8);
            reinterpret_cast<float4*>(yb)[0] = ldf4(p1);
            reinterpret_cast<float4*>(yb)[1] = ldf4(p1 + 4);
            reinterpret_cast<float4*>(yb)[2] = ldf4(p1 + 8);
        }
        float o[8];
#pragma unroll
        for (int r = 0; r < 8; ++r) {
            const int jr = ((r + 1) >> 1) + 2;
            const int kb = 7 - (r & 1);
            float acc = 0.f;
#pragma unroll
            for (int q = 0; q < 4; ++q) {
                acc = fmaf(ya[jr + q], lp[kb - 2 * q], acc);
                acc = fmaf(yb[jr + q], hp[kb - 2 * q], acc);
            }
            o[r] = acc;
        }
        stf4(ob + i0,     make_float4(o[0], o[1], o[2], o[3]));
        stf4(ob + i0 + 4, make_float4(o[4], o[5], o[6], o[7]));
    }
}

__global__ __launch_bounds__(TPB, 8) void wpt_fused(
    const float* __restrict__ x,
    const float* __restrict__ K1, const float* __restrict__ K2,
    const float* __restrict__ K3, const float* __restrict__ K4,
    const float* __restrict__ K5,
    const float* __restrict__ B1, const float* __restrict__ B2,
    const float* __restrict__ B3, const float* __restrict__ B4,
    const float* __restrict__ B5,
    float* __restrict__ out)
{
    __shared__ __align__(16) float bufA[2528];
    __shared__ __align__(16) float bufB[2512];
    __shared__ float bss[62];

    const int tid   = threadIdx.x;
    const int batch = blockIdx.x >> 4;
    const int cid   = blockIdx.x & 15;
    const int s     = cid * C0;

    // Filters in SGPRs: K1 = [lp | hp], 8 taps each (all levels use only these rows)
    float lp[8], hp[8];
#pragma unroll
    for (int t = 0; t < 8; ++t) {
        lp[t] = rfl(K1[t]);
        hp[t] = rfl(K1[8 + t]);
    }

    // Stage biases (pre-scaled by 10*log2(e))
    {
        const float* bin[5] = {B1, B2, B3, B4, B5};
        const int boff[5] = {0, 2, 6, 14, 30};
#pragma unroll
        for (int l = 0; l < 5; ++l)
            for (int i = tid; i < (2 << l); i += TPB) bss[boff[l] + i] = SCG * bin[l][i];
    }

    const float* xb = x + batch * NSEQ;
    float* ob = out + batch * NSEQ + s;

    if (cid == 0 || cid == 15)
        run_chunk<true >(xb, ob, s, bufA, bufB, lp, hp, bss);
    else
        run_chunk<false>(xb, ob, s, bufA, bufB, lp, hp, bss);
}

extern "C" void kernel_launch(void* const* d_in, const int* in_sizes, int n_in,
                              void* d_out, int out_size, void* d_ws, size_t ws_size,
                              hipStream_t stream) {
    const int nbatch = in_sizes[0] / NSEQ;
    wpt_fused<<<dim3(nbatch * (NSEQ / C0)), dim3(TPB), 0, stream>>>(
        (const float*)d_in[0],
        (const float*)d_in[1], (const float*)d_in[2],
        (const float*)d_in[3], (const float*)d_in[4],
        (const float*)d_in[5],
        (const float*)d_in[6], (const float*)d_in[7],
        (const float*)d_in[8], (const float*)d_in[9],
        (const float*)d_in[10],
        (float*)d_out);
}